// Round 1
// baseline (538.874 us; speedup 1.0000x reference)
//
#include <hip/hip_runtime.h>
#include <hip/hip_bf16.h>

// Problem constants
#define NCHUNK 32
#define NBATCH 64
#define HALF   128
#define SIZE   (2 * HALF)          // 256
#define NROWS  (NCHUNK * NBATCH)   // 2048
#define C_SCALE 1e-4f
#define M_SCALE 1e-5f

// ---------------------------------------------------------------------------
// Kernel 1: build Jb (256x256) into the first J copy (J[0][0]).
//   Jb[:128, :]        = [0 | I]
//   Jb[128:, :128]     = ku (tridiagonal)
//   Jb[128:, 128:]     = kv (tridiagonal)
// grid = 256 (one block per row r), block = 256 (one thread per col c)
// ---------------------------------------------------------------------------
__global__ void jb_kernel(const float* __restrict__ K,
                          const float* __restrict__ C,
                          const float* __restrict__ M,
                          float* __restrict__ Jb) {
    int r = blockIdx.x;
    int c = threadIdx.x;
    float val = 0.0f;
    if (r < HALF) {
        val = (c == r + HALF) ? 1.0f : 0.0f;
    } else {
        int i = r - HALF;
        float Mi = M[i] * M_SCALE;
        bool isV = (c >= HALF);
        int  j   = isV ? (c - HALF) : c;
        // A[x] = K[x] (u block) or Cs[x] = C[x]*C_SCALE (v block)
        float scale = isV ? C_SCALE : 1.0f;
        const float* __restrict__ A = isV ? C : K;
        if (j == i) {
            val = -A[i] * scale / Mi;
            if (i >= 1) val += -A[i - 1] * scale / Mi;
        } else if (j == i + 1 && i < HALF - 1) {
            val = A[i] * scale / Mi;           // superdiag: A[i]/Ms[i]
        } else if (j == i - 1) {
            val = A[i - 1] * scale / Mi;       // subdiag:   A[i-1]/Ms[i]
        }
    }
    Jb[r * SIZE + c] = val;
}

// ---------------------------------------------------------------------------
// Kernel 2: broadcast the 256KB Jb block (float4-granular) to the remaining
// 2047 copies. src stays L2-resident; dst is a pure streaming write.
// ---------------------------------------------------------------------------
__global__ void bcast_kernel(const float4* __restrict__ src,
                             float4* __restrict__ dst,
                             long total4) {
    long idx    = (long)blockIdx.x * blockDim.x + threadIdx.x;
    long stride = (long)gridDim.x * blockDim.x;
    for (; idx < total4; idx += stride) {
        dst[idx] = src[idx & 16383];   // 16384 float4 per copy (64KB floats)
    }
}

// ---------------------------------------------------------------------------
// Kernel 3: ydot. One block per (chunk,batch) row, 128 threads.
//   ydot[row][i]       = v[i]
//   ydot[row][128 + i] = vdot[i]
// ---------------------------------------------------------------------------
__global__ void ydot_kernel(const float* __restrict__ t,
                            const float* __restrict__ y,
                            const float* __restrict__ K,
                            const float* __restrict__ C,
                            const float* __restrict__ M,
                            float* __restrict__ out) {
    int row = blockIdx.x;          // 0..2047
    int i   = threadIdx.x;         // 0..127
    const float* yr = y + (long)row * SIZE;

    float u = yr[i];
    float v = yr[HALF + i];
    out[(long)row * SIZE + i] = v;  // ydot first half = v

    float Mi   = M[i] * M_SCALE;
    float vdot = 0.0f;
    if (i < HALF - 1) {
        float f = K[i] * (yr[i + 1] - u) + C[i] * C_SCALE * (yr[HALF + i + 1] - v);
        vdot += f / Mi;
    }
    if (i >= 1) {
        float fm = K[i - 1] * (u - yr[i - 1]) + C[i - 1] * C_SCALE * (v - yr[HALF + i - 1]);
        vdot -= fm / Mi;
    }
    if (i == HALF - 1) {
        vdot += -(K[HALF - 1] * u + C[HALF - 1] * C_SCALE * v) / Mi;
    }
    if (i == 0) {
        vdot += sinf(t[row]) / Mi;
    }
    out[(long)row * SIZE + HALF + i] = vdot;
}

extern "C" void kernel_launch(void* const* d_in, const int* in_sizes, int n_in,
                              void* d_out, int out_size, void* d_ws, size_t ws_size,
                              hipStream_t stream) {
    const float* t = (const float*)d_in[0];   // (32,64)
    const float* y = (const float*)d_in[1];   // (32,64,256)
    const float* K = (const float*)d_in[2];   // (128,)
    const float* C = (const float*)d_in[3];   // (128,)
    const float* M = (const float*)d_in[4];   // (128,)

    float* out  = (float*)d_out;
    // Output layout: ydot (2048*256 floats) then J (2048*256*256 floats)
    float* Jout = out + (long)NROWS * SIZE;   // first copy J[0][0] lives here

    // 1) Jb -> first J copy
    jb_kernel<<<SIZE, SIZE, 0, stream>>>(K, C, M, Jout);

    // 2) broadcast to remaining 2047 copies
    const float4* src = (const float4*)Jout;
    float4*       dst = (float4*)Jout + 16384;          // skip copy 0
    long total4 = (long)(NROWS - 1) * 16384;            // 2047 * 16384
    bcast_kernel<<<2048, 256, 0, stream>>>(src, dst, total4);

    // 3) ydot
    ydot_kernel<<<NROWS, HALF, 0, stream>>>(t, y, K, C, M, out);
}

// Round 2
// 531.222 us; speedup vs baseline: 1.0144x; 1.0144x over previous
//
#include <hip/hip_runtime.h>
#include <hip/hip_bf16.h>

// Problem constants
#define NCHUNK 32
#define NBATCH 64
#define HALF   128
#define SIZE   (2 * HALF)          // 256
#define NROWS  (NCHUNK * NBATCH)   // 2048
#define C_SCALE 1e-4f
#define M_SCALE 1e-5f

// Jb is 256x256 floats = 16384 float4 = 256 KB.
#define JB_F4   16384              // float4 elements per J copy
#define COPIES_PER_GROUP 64        // each block writes its slice to 64 copies

// ---------------------------------------------------------------------------
// J kernel: compute Jb values in registers, then pure-store broadcast.
//   grid = 2048 blocks (64 slice-groups x 32 copy-groups), 256 threads.
//   Block b: slice s = b & 63  -> owns float4 range [s*256, s*256+255] of Jb
//            group g = b >> 6  -> writes copies [g*64, g*64+63]
//   Per store instruction: 256 threads x 16B = 4 KB contiguous. No loads in
//   the store loop -> no vmcnt dependency chain -> write-BW bound.
// ---------------------------------------------------------------------------
__global__ __launch_bounds__(256) void j_kernel(const float* __restrict__ K,
                                                const float* __restrict__ C,
                                                const float* __restrict__ M,
                                                float* __restrict__ Jout) {
    int tid = threadIdx.x;
    int b   = blockIdx.x;
    int s   = b & 63;          // slice within Jb
    int g   = b >> 6;          // copy group
    int o4  = s * 256 + tid;   // this thread's float4 index within Jb (0..16383)
    int r   = o4 >> 6;         // row (0..255); 64 float4 per row
    int c0  = (o4 & 63) << 2;  // first column of this float4

    float vals[4];
    if (r < HALF) {
        // top half: [0 | I]
        #pragma unroll
        for (int k = 0; k < 4; ++k)
            vals[k] = (c0 + k == r + HALF) ? 1.0f : 0.0f;
    } else {
        int   i     = r - HALF;
        float invMi = 1.0f / (M[i] * M_SCALE);
        #pragma unroll
        for (int k = 0; k < 4; ++k) {
            int  c   = c0 + k;
            bool isV = (c >= HALF);
            int  j   = isV ? (c - HALF) : c;
            float scale = isV ? C_SCALE : 1.0f;
            const float* __restrict__ A = isV ? C : K;
            float v = 0.0f;
            if (j == i) {
                v = -A[i] * scale * invMi;
                if (i >= 1) v += -A[i - 1] * scale * invMi;
            } else if (j == i + 1 && i < HALF - 1) {
                v = A[i] * scale * invMi;      // superdiag: A[i]/Ms[i]
            } else if (j == i - 1) {
                v = A[i - 1] * scale * invMi;  // subdiag:   A[i-1]/Ms[i]
            }
            vals[k] = v;
        }
    }
    float4 val = make_float4(vals[0], vals[1], vals[2], vals[3]);

    float4* dst = (float4*)Jout + (long)g * COPIES_PER_GROUP * JB_F4 + o4;
    #pragma unroll
    for (int cp = 0; cp < COPIES_PER_GROUP; ++cp) {
        dst[(long)cp * JB_F4] = val;   // 64 independent pure stores
    }
}

// ---------------------------------------------------------------------------
// ydot. One block per (chunk,batch) row, 128 threads.
//   ydot[row][i]       = v[i]
//   ydot[row][128 + i] = vdot[i]
// ---------------------------------------------------------------------------
__global__ void ydot_kernel(const float* __restrict__ t,
                            const float* __restrict__ y,
                            const float* __restrict__ K,
                            const float* __restrict__ C,
                            const float* __restrict__ M,
                            float* __restrict__ out) {
    int row = blockIdx.x;          // 0..2047
    int i   = threadIdx.x;         // 0..127
    const float* yr = y + (long)row * SIZE;

    float u = yr[i];
    float v = yr[HALF + i];
    out[(long)row * SIZE + i] = v;  // ydot first half = v

    float Mi   = M[i] * M_SCALE;
    float vdot = 0.0f;
    if (i < HALF - 1) {
        float f = K[i] * (yr[i + 1] - u) + C[i] * C_SCALE * (yr[HALF + i + 1] - v);
        vdot += f / Mi;
    }
    if (i >= 1) {
        float fm = K[i - 1] * (u - yr[i - 1]) + C[i - 1] * C_SCALE * (v - yr[HALF + i - 1]);
        vdot -= fm / Mi;
    }
    if (i == HALF - 1) {
        vdot += -(K[HALF - 1] * u + C[HALF - 1] * C_SCALE * v) / Mi;
    }
    if (i == 0) {
        vdot += sinf(t[row]) / Mi;
    }
    out[(long)row * SIZE + HALF + i] = vdot;
}

extern "C" void kernel_launch(void* const* d_in, const int* in_sizes, int n_in,
                              void* d_out, int out_size, void* d_ws, size_t ws_size,
                              hipStream_t stream) {
    const float* t = (const float*)d_in[0];   // (32,64)
    const float* y = (const float*)d_in[1];   // (32,64,256)
    const float* K = (const float*)d_in[2];   // (128,)
    const float* C = (const float*)d_in[3];   // (128,)
    const float* M = (const float*)d_in[4];   // (128,)

    float* out  = (float*)d_out;
    // Output layout: ydot (2048*256 floats) then J (2048*256*256 floats)
    float* Jout = out + (long)NROWS * SIZE;

    // J: compute-in-register + pure-store broadcast of all 2048 copies
    j_kernel<<<NROWS, 256, 0, stream>>>(K, C, M, Jout);

    // ydot
    ydot_kernel<<<NROWS, HALF, 0, stream>>>(t, y, K, C, M, out);
}